// Round 20
// baseline (990.188 us; speedup 1.0000x reference)
//
#include <hip/hip_runtime.h>

__device__ __forceinline__ float bcast_lane(float v, int lane) {
    return __int_as_float(__builtin_amdgcn_readlane(__float_as_int(v), lane));
}

#define NCHUNK 32
#define NRANGE 16
#define MAXRANGE 6250  // >= ceil(N/NRANGE) for N=100000

// ---- LDS-histogram hist+rank, high-occupancy geometry (512 blk x 1024) ---
__global__ void k_lhist(const int* __restrict__ col, int* __restrict__ lrank,
                        int* __restrict__ gcounts, int E, int N) {
    __shared__ int cnt[MAXRANGE];
    int j = blockIdx.x & 31, r = blockIdx.x >> 5;
    int lo = (int)((long long)N * r / NRANGE);
    int hi = (int)((long long)N * (r + 1) / NRANGE);
    int len = hi - lo;
    for (int i = threadIdx.x; i < len; i += 1024) cnt[i] = 0;
    __syncthreads();
    long long c0 = (long long)E * j / NCHUNK;
    long long c1 = (long long)E * (j + 1) / NCHUNK;
    for (long long e = c0 + threadIdx.x; e < c1; e += 1024) {
        int c = col[e];
        if (c >= lo && c < hi)
            lrank[e] = atomicAdd(&cnt[c - lo], 1);
    }
    __syncthreads();
    for (int i = threadIdx.x; i < len; i += 1024)
        gcounts[(size_t)j * N + lo + i] = cnt[i];
}

// ---- gcounts -> per-chunk exclusive bases (in place) + total deg ---------
__global__ void k_gbase(int* __restrict__ gcounts, int* __restrict__ deg, int N) {
    int i = blockIdx.x * 256 + threadIdx.x;
    if (i >= N) return;
    int running = 0;
#pragma unroll
    for (int j = 0; j < NCHUNK; j++) {
        size_t idx = (size_t)j * N + i;
        int t = gcounts[idx];
        gcounts[idx] = running;
        running += t;
    }
    deg[i] = running;
}

// block-level exclusive scan (256 elems / block)
__global__ void k_scan1(const int* __restrict__ deg, int* __restrict__ part,
                        int* __restrict__ bsum, int N) {
    __shared__ int sm[256];
    int t = threadIdx.x;
    int i = blockIdx.x * 256 + t;
    int v = (i < N) ? deg[i] : 0;
    sm[t] = v;
    __syncthreads();
    for (int d = 1; d < 256; d <<= 1) {
        int add = (t >= d) ? sm[t - d] : 0;
        __syncthreads();
        sm[t] += add;
        __syncthreads();
    }
    if (i < N) part[i] = sm[t] - v;  // exclusive
    if (t == 255) bsum[blockIdx.x] = sm[255];
}

__global__ void k_scan2(int* __restrict__ bsum, int nb) {
    __shared__ int sm[512];
    int t = threadIdx.x;
    int v = (t < nb) ? bsum[t] : 0;
    sm[t] = v;
    __syncthreads();
    for (int d = 1; d < 512; d <<= 1) {
        int add = (t >= d) ? sm[t - d] : 0;
        __syncthreads();
        sm[t] += add;
        __syncthreads();
    }
    if (t < nb) bsum[t] = sm[t] - v;
}

// scan finalize + dinv + y4 (layer-1 pre-agg in 3-dim space), fused
__global__ void k_scan3d(const int* __restrict__ part, const int* __restrict__ bsum,
                         const int* __restrict__ deg, const float* __restrict__ x,
                         int* __restrict__ off, float* __restrict__ dinv,
                         float4* __restrict__ y4, int N, int E) {
    int i = blockIdx.x * 256 + threadIdx.x;
    if (i < N) {
        int o = part[i] + bsum[blockIdx.x];
        off[i] = o;
        float d = rsqrtf((float)deg[i] + 1.0f);
        dinv[i] = d;
        y4[i] = make_float4(d * x[i * 3 + 0], d * x[i * 3 + 1], d * x[i * 3 + 2], 0.f);
    }
    if (i == 0) off[N] = E;
}

// pos[e] = off[c] + gcounts[chunk(e)][c] + lrank[e]  (fully atomic-free)
__global__ void k_posL(const int* __restrict__ col, const int* __restrict__ lrank,
                       const int* __restrict__ off, const int* __restrict__ gc,
                       int* __restrict__ pos, int E, int N) {
    int e = blockIdx.x * 256 + threadIdx.x;
    if (e < E) {
        int c = col[e];
        int j = (int)((32LL * e) / E);
        pos[e] = off[c] + gc[(size_t)j * N + c] + lrank[e];
    }
}

// atomic-free XCD-partitioned scatter: rowlist[pos[e]] = row[e].
__global__ void k_fillr(const int* __restrict__ row, const int* __restrict__ pos,
                        int* __restrict__ rowlist, int E) {
    int r = blockIdx.x & 7;
    int chunk = blockIdx.x >> 3;
    int nchunks = gridDim.x >> 3;
    int plo = (int)((long long)E * r >> 3);
    int phi = (int)((long long)E * (r + 1) >> 3);
    long long c0 = (long long)E * chunk / nchunks;
    long long c1 = (long long)E * (chunk + 1) / nchunks;
    for (long long e = c0 + threadIdx.x; e < c1; e += blockDim.x) {
        int p = __builtin_nontemporal_load(&pos[e]);
        if (p >= plo && p < phi)
            rowlist[p] = __builtin_nontemporal_load(&row[e]);
    }
}

// ---- fused layer1+lin2 ----------------------------------------------------
__global__ void k_layer12(const float4* __restrict__ y4, const int* __restrict__ off,
                          const int* __restrict__ rowlist, const float* __restrict__ dinv,
                          const float* __restrict__ W1, const float* __restrict__ b1,
                          const float* __restrict__ W2, float* __restrict__ g2, int N) {
    __shared__ float W2l[4096];
    __shared__ float W1l[192];
    int tid = threadIdx.x;
    for (int i = tid; i < 4096; i += 256) W2l[i] = W2[i];
    if (tid < 192) W1l[tid] = W1[tid];
    __syncthreads();
    int wave = tid >> 6, lane = tid & 63;
    int n = blockIdx.x * 4 + wave;
    if (n >= N) return;
    int s = off[n], epos = off[n + 1];
    float ax, ay, az;
    {
        float4 self = y4[n];
        ax = (lane == 0) ? self.x : 0.f;
        ay = (lane == 0) ? self.y : 0.f;
        az = (lane == 0) ? self.z : 0.f;
    }
    for (int j = s + lane; j < epos; j += 64) {
        float4 t = y4[rowlist[j]];
        ax += t.x; ay += t.y; az += t.z;
    }
#pragma unroll
    for (int d = 1; d < 64; d <<= 1) {
        ax += __shfl_xor(ax, d);
        ay += __shfl_xor(ay, d);
        az += __shfl_xor(az, d);
    }
    float dn = dinv[n];
    float h1 = fmaxf(fmaf(dn, ax * W1l[lane] + ay * W1l[64 + lane] + az * W1l[128 + lane],
                          b1[lane]), 0.0f);
    float acc2 = 0.f;
#pragma unroll
    for (int k = 0; k < 64; k++) {
        float hk = bcast_lane(h1, k);
        acc2 = fmaf(hk, W2l[k * 64 + lane], acc2);
    }
    g2[(size_t)n * 64 + lane] = dn * acc2;
}

// ---- gather-aggregate (LDS-free, latency-bound -> 8-deep MLP) ------------
__global__ void k_gather(const float* __restrict__ g, const int* __restrict__ off,
                         const int* __restrict__ rl, const float* __restrict__ dinv,
                         const float* __restrict__ b, float* __restrict__ h, int N) {
    int tid = threadIdx.x;
    int wave = tid >> 6, lane = tid & 63;
    int n = blockIdx.x * 4 + wave;
    if (n >= N) return;
    int s = off[n], epos = off[n + 1];
    float a0 = g[(size_t)n * 64 + lane];
    float a1 = 0.f, a2 = 0.f, a3 = 0.f;
    float a4 = 0.f, a5 = 0.f, a6 = 0.f, a7 = 0.f;
    int j = s;
    for (; j + 7 < epos; j += 8) {
        int r0 = rl[j],     r1 = rl[j + 1], r2 = rl[j + 2], r3 = rl[j + 3];
        int r4 = rl[j + 4], r5 = rl[j + 5], r6 = rl[j + 6], r7 = rl[j + 7];
        a0 += g[(size_t)r0 * 64 + lane];
        a1 += g[(size_t)r1 * 64 + lane];
        a2 += g[(size_t)r2 * 64 + lane];
        a3 += g[(size_t)r3 * 64 + lane];
        a4 += g[(size_t)r4 * 64 + lane];
        a5 += g[(size_t)r5 * 64 + lane];
        a6 += g[(size_t)r6 * 64 + lane];
        a7 += g[(size_t)r7 * 64 + lane];
    }
    for (; j < epos; j++) a1 += g[(size_t)rl[j] * 64 + lane];
    float acc = ((a0 + a1) + (a2 + a3)) + ((a4 + a5) + (a6 + a7));
    h[(size_t)n * 64 + lane] = fmaxf(fmaf(dinv[n], acc, b[lane]), 0.0f);
}

// ---- edge-MLP precompute: PERSISTENT, readlane broadcast, and Wa/Wb
//      INTERLEAVED as float2 so each lane's two weight reads are ONE
//      ds_read_b64 (8 contiguous bytes) instead of two ds_read_b32 16KB
//      apart. Halves LDS issue count (the kernel's bound: 128 b32/node
//      ~742cyc -> 64 b64 ~420cyc). Loop structure unchanged (round-16's
//      float4+loop-reshape regressed; this isolates the layout).
__global__ void k_lin3(float* __restrict__ h, const float* __restrict__ W3,
                       const float* __restrict__ b3, float* __restrict__ u, int N) {
    __shared__ float2 Wab[4096];  // 32KB: Wab[k*64+f] = {Wa[k][f], Wb[k][f]}
    int tid = threadIdx.x;
    for (int i = tid; i < 4096; i += 256)
        Wab[i] = make_float2(W3[i], W3[4096 + i]);
    __syncthreads();
    int wave = tid >> 6, lane = tid & 63;
    int gid = blockIdx.x * 4 + wave;
    int stride = gridDim.x * 4;
    float bb = b3[lane];
    for (int n = gid; n < N; n += stride) {
        float hv = h[(size_t)n * 64 + lane];
        float ua = bb, va = 0.f;
#pragma unroll
        for (int k = 0; k < 64; k++) {
            float hk = bcast_lane(hv, k);
            float2 w = Wab[k * 64 + lane];
            ua = fmaf(hk, w.x, ua);
            va = fmaf(hk, w.y, va);
        }
        u[(size_t)n * 64 + lane] = ua;
        h[(size_t)n * 64 + lane] = va;  // v in place over h2 (lane-local row)
    }
}

// ---- edge scorer, CSR order, SEQUENTIAL writes to tmp --------------------
__global__ void k_edge_csr(const float4* __restrict__ u4, const float4* __restrict__ v4,
                           const int* __restrict__ off, const int* __restrict__ rowlist,
                           const float4* __restrict__ w44, const float* __restrict__ b4,
                           float* __restrict__ tmp, int N) {
    int tid = threadIdx.x;
    int wave = tid >> 6, lane = tid & 63;
    int n = blockIdx.x * 4 + wave;
    if (n >= N) return;
    int c16 = lane & 15, grp = lane >> 4;
    int s = off[n], epos = off[n + 1];
    float4 vv = v4[(size_t)n * 16 + c16];
    float4 w = w44[c16];
    float bb = b4[0];
    for (int j0 = s; j0 < epos; j0 += 16) {
        int ja = j0 + grp, jb = j0 + 4 + grp, jc = j0 + 8 + grp, jd = j0 + 12 + grp;
        bool va_ = ja < epos, vb_ = jb < epos, vc_ = jc < epos, vd_ = jd < epos;
        int ra = va_ ? rowlist[ja] : 0;
        int rb = vb_ ? rowlist[jb] : 0;
        int rc = vc_ ? rowlist[jc] : 0;
        int rd = vd_ ? rowlist[jd] : 0;
        float4 a = u4[(size_t)ra * 16 + c16];
        float4 b = u4[(size_t)rb * 16 + c16];
        float4 c = u4[(size_t)rc * 16 + c16];
        float4 d = u4[(size_t)rd * 16 + c16];
        float sa = fmaxf(a.x + vv.x, 0.f) * w.x + fmaxf(a.y + vv.y, 0.f) * w.y +
                   fmaxf(a.z + vv.z, 0.f) * w.z + fmaxf(a.w + vv.w, 0.f) * w.w;
        float sb = fmaxf(b.x + vv.x, 0.f) * w.x + fmaxf(b.y + vv.y, 0.f) * w.y +
                   fmaxf(b.z + vv.z, 0.f) * w.z + fmaxf(b.w + vv.w, 0.f) * w.w;
        float sc = fmaxf(c.x + vv.x, 0.f) * w.x + fmaxf(c.y + vv.y, 0.f) * w.y +
                   fmaxf(c.z + vv.z, 0.f) * w.z + fmaxf(c.w + vv.w, 0.f) * w.w;
        float sd = fmaxf(d.x + vv.x, 0.f) * w.x + fmaxf(d.y + vv.y, 0.f) * w.y +
                   fmaxf(d.z + vv.z, 0.f) * w.z + fmaxf(d.w + vv.w, 0.f) * w.w;
        sa += __shfl_xor(sa, 1); sa += __shfl_xor(sa, 2);
        sa += __shfl_xor(sa, 4); sa += __shfl_xor(sa, 8);
        sb += __shfl_xor(sb, 1); sb += __shfl_xor(sb, 2);
        sb += __shfl_xor(sb, 4); sb += __shfl_xor(sb, 8);
        sc += __shfl_xor(sc, 1); sc += __shfl_xor(sc, 2);
        sc += __shfl_xor(sc, 4); sc += __shfl_xor(sc, 8);
        sd += __shfl_xor(sd, 1); sd += __shfl_xor(sd, 2);
        sd += __shfl_xor(sd, 4); sd += __shfl_xor(sd, 8);
        if (c16 == 0) {
            if (va_) tmp[ja] = sa + bb;
            if (vb_) tmp[jb] = sb + bb;
            if (vc_) tmp[jc] = sc + bb;
            if (vd_) tmp[jd] = sd + bb;
        }
    }
}

// ---- final permute: out[e] = tmp[pos[e]] ---------------------------------
__global__ void k_perm(const float* __restrict__ tmp, const int* __restrict__ pos,
                       float* __restrict__ out, int E) {
    int e = blockIdx.x * blockDim.x + threadIdx.x;
    if (e < E) out[e] = tmp[pos[e]];
}

extern "C" void kernel_launch(void* const* d_in, const int* in_sizes, int n_in,
                              void* d_out, int out_size, void* d_ws, size_t ws_size,
                              hipStream_t stream) {
    const float* x  = (const float*)d_in[0];
    const int*   ei = (const int*)d_in[1];
    const float* W1 = (const float*)d_in[2];
    const float* b1 = (const float*)d_in[3];
    const float* W2 = (const float*)d_in[4];
    const float* b2 = (const float*)d_in[5];
    const float* W3 = (const float*)d_in[6];
    const float* b3 = (const float*)d_in[7];
    const float* W4 = (const float*)d_in[8];
    const float* b4 = (const float*)d_in[9];
    int N = in_sizes[0] / 3;
    int E = in_sizes[1] / 2;
    const int* row = ei;
    const int* col = ei + E;
    float* out = (float*)d_out;

    char* ws = (char*)d_ws;
    size_t off_b = 0;
    auto alloc = [&](size_t bytes) {
        void* p = ws + off_b;
        off_b += (bytes + 255) & ~(size_t)255;
        return p;
    };
    float* dinv    = (float*)alloc((size_t)N * 4);
    int*   offs    = (int*)alloc((size_t)(N + 1) * 4);
    int*   bsum    = (int*)alloc(512 * 4);
    float* bufA    = (float*)alloc((size_t)N * 64 * 4);   // ints; g2; u
    float* bufB    = (float*)alloc((size_t)N * 64 * 4);   // y4+lrank; h2/v
    int*   rowlist = (int*)alloc((size_t)E * 4);
    int*   pos     = (int*)alloc((size_t)E * 4);
    float* tmp     = (float*)alloc((size_t)E * 4);

    // aliases into bufA (all dead before k_layer12 writes g2=bufA):
    int* part    = (int*)bufA;              // N
    int* deg     = (int*)bufA + N;          // N
    int* gcounts = (int*)bufA + 2 * N;      // 32N = 12.8MB (fits: 34N < 64N)
    // aliases into bufB (dead before k_gather writes h2=bufB):
    float4* y4   = (float4*)bufB;           // 4N floats
    int*   lrank = (int*)bufB + (size_t)4 * N;  // E ints

    dim3 B(256);
    int nbN     = (N + 255) / 256;
    int nbE     = (E + 255) / 256;
    int nbNode4 = (N + 3) / 4;

    // --- CSR build (LDS-histogram, zero global atomics) + normalization ---
    k_lhist<<<NRANGE * NCHUNK, 1024, 0, stream>>>(col, lrank, gcounts, E, N);
    k_gbase<<<nbN, B, 0, stream>>>(gcounts, deg, N);
    k_scan1<<<nbN, B, 0, stream>>>(deg, part, bsum, N);
    k_scan2<<<1, 512, 0, stream>>>(bsum, nbN);
    k_scan3d<<<nbN, B, 0, stream>>>(part, bsum, deg, x, offs, dinv, y4, N, E);
    k_posL<<<nbE, B, 0, stream>>>(col, lrank, offs, gcounts, pos, E, N);
    k_fillr<<<2048, B, 0, stream>>>(row, pos, rowlist, E);

    // --- fused layer1 + lin2: writes g2=bufA ---
    k_layer12<<<nbNode4, B, 0, stream>>>(y4, offs, rowlist, dinv, W1, b1, W2, bufA, N);
    // --- layer 2 aggregate: h2=bufB ---
    k_gather<<<nbNode4, B, 0, stream>>>(bufA, offs, rowlist, dinv, b2, bufB, N);
    // --- edge MLP precompute: u=bufA (over dead g2), v in place over h2 ---
    k_lin3<<<1280, B, 0, stream>>>(bufB, W3, b3, bufA, N);
    // --- edge scorer to tmp (CSR order), then permute to edge order ---
    k_edge_csr<<<nbNode4, B, 0, stream>>>((const float4*)bufA, (const float4*)bufB,
                                          offs, rowlist, (const float4*)W4, b4, tmp, N);
    k_perm<<<nbE, B, 0, stream>>>(tmp, pos, out, E);
}

// Round 21
// 536.127 us; speedup vs baseline: 1.8469x; 1.8469x over previous
//
#include <hip/hip_runtime.h>

__device__ __forceinline__ float bcast_lane(float v, int lane) {
    return __int_as_float(__builtin_amdgcn_readlane(__float_as_int(v), lane));
}

#define NCHUNK 32
#define NRANGE 16
#define MAXRANGE 6250  // >= ceil(N/NRANGE) for N=100000

// ---- LDS-histogram hist+rank, high-occupancy geometry (512 blk x 1024) ---
__global__ void k_lhist(const int* __restrict__ col, int* __restrict__ lrank,
                        int* __restrict__ gcounts, int E, int N) {
    __shared__ int cnt[MAXRANGE];
    int j = blockIdx.x & 31, r = blockIdx.x >> 5;
    int lo = (int)((long long)N * r / NRANGE);
    int hi = (int)((long long)N * (r + 1) / NRANGE);
    int len = hi - lo;
    for (int i = threadIdx.x; i < len; i += 1024) cnt[i] = 0;
    __syncthreads();
    long long c0 = (long long)E * j / NCHUNK;
    long long c1 = (long long)E * (j + 1) / NCHUNK;
    for (long long e = c0 + threadIdx.x; e < c1; e += 1024) {
        int c = col[e];
        if (c >= lo && c < hi)
            lrank[e] = atomicAdd(&cnt[c - lo], 1);
    }
    __syncthreads();
    for (int i = threadIdx.x; i < len; i += 1024)
        gcounts[(size_t)j * N + lo + i] = cnt[i];
}

// ---- gcounts -> per-chunk exclusive bases (in place) + total deg ---------
__global__ void k_gbase(int* __restrict__ gcounts, int* __restrict__ deg, int N) {
    int i = blockIdx.x * 256 + threadIdx.x;
    if (i >= N) return;
    int running = 0;
#pragma unroll
    for (int j = 0; j < NCHUNK; j++) {
        size_t idx = (size_t)j * N + i;
        int t = gcounts[idx];
        gcounts[idx] = running;
        running += t;
    }
    deg[i] = running;
}

// block-level exclusive scan (256 elems / block)
__global__ void k_scan1(const int* __restrict__ deg, int* __restrict__ part,
                        int* __restrict__ bsum, int N) {
    __shared__ int sm[256];
    int t = threadIdx.x;
    int i = blockIdx.x * 256 + t;
    int v = (i < N) ? deg[i] : 0;
    sm[t] = v;
    __syncthreads();
    for (int d = 1; d < 256; d <<= 1) {
        int add = (t >= d) ? sm[t - d] : 0;
        __syncthreads();
        sm[t] += add;
        __syncthreads();
    }
    if (i < N) part[i] = sm[t] - v;  // exclusive
    if (t == 255) bsum[blockIdx.x] = sm[255];
}

__global__ void k_scan2(int* __restrict__ bsum, int nb) {
    __shared__ int sm[512];
    int t = threadIdx.x;
    int v = (t < nb) ? bsum[t] : 0;
    sm[t] = v;
    __syncthreads();
    for (int d = 1; d < 512; d <<= 1) {
        int add = (t >= d) ? sm[t - d] : 0;
        __syncthreads();
        sm[t] += add;
        __syncthreads();
    }
    if (t < nb) bsum[t] = sm[t] - v;
}

// scan finalize + dinv + y4 (layer-1 pre-agg in 3-dim space), fused
__global__ void k_scan3d(const int* __restrict__ part, const int* __restrict__ bsum,
                         const int* __restrict__ deg, const float* __restrict__ x,
                         int* __restrict__ off, float* __restrict__ dinv,
                         float4* __restrict__ y4, int N, int E) {
    int i = blockIdx.x * 256 + threadIdx.x;
    if (i < N) {
        int o = part[i] + bsum[blockIdx.x];
        off[i] = o;
        float d = rsqrtf((float)deg[i] + 1.0f);
        dinv[i] = d;
        y4[i] = make_float4(d * x[i * 3 + 0], d * x[i * 3 + 1], d * x[i * 3 + 2], 0.f);
    }
    if (i == 0) off[N] = E;
}

// pos[e] = off[c] + gcounts[chunk(e)][c] + lrank[e]  (fully atomic-free)
__global__ void k_posL(const int* __restrict__ col, const int* __restrict__ lrank,
                       const int* __restrict__ off, const int* __restrict__ gc,
                       int* __restrict__ pos, int E, int N) {
    int e = blockIdx.x * 256 + threadIdx.x;
    if (e < E) {
        int c = col[e];
        int j = (int)((32LL * e) / E);
        pos[e] = off[c] + gc[(size_t)j * N + c] + lrank[e];
    }
}

// atomic-free XCD-partitioned scatter: rowlist[pos[e]] = row[e].
__global__ void k_fillr(const int* __restrict__ row, const int* __restrict__ pos,
                        int* __restrict__ rowlist, int E) {
    int r = blockIdx.x & 7;
    int chunk = blockIdx.x >> 3;
    int nchunks = gridDim.x >> 3;
    int plo = (int)((long long)E * r >> 3);
    int phi = (int)((long long)E * (r + 1) >> 3);
    long long c0 = (long long)E * chunk / nchunks;
    long long c1 = (long long)E * (chunk + 1) / nchunks;
    for (long long e = c0 + threadIdx.x; e < c1; e += blockDim.x) {
        int p = __builtin_nontemporal_load(&pos[e]);
        if (p >= plo && p < phi)
            rowlist[p] = __builtin_nontemporal_load(&row[e]);
    }
}

// ---- fused layer1+lin2 ----------------------------------------------------
__global__ void k_layer12(const float4* __restrict__ y4, const int* __restrict__ off,
                          const int* __restrict__ rowlist, const float* __restrict__ dinv,
                          const float* __restrict__ W1, const float* __restrict__ b1,
                          const float* __restrict__ W2, float* __restrict__ g2, int N) {
    __shared__ float W2l[4096];
    __shared__ float W1l[192];
    int tid = threadIdx.x;
    for (int i = tid; i < 4096; i += 256) W2l[i] = W2[i];
    if (tid < 192) W1l[tid] = W1[tid];
    __syncthreads();
    int wave = tid >> 6, lane = tid & 63;
    int n = blockIdx.x * 4 + wave;
    if (n >= N) return;
    int s = off[n], epos = off[n + 1];
    float ax, ay, az;
    {
        float4 self = y4[n];
        ax = (lane == 0) ? self.x : 0.f;
        ay = (lane == 0) ? self.y : 0.f;
        az = (lane == 0) ? self.z : 0.f;
    }
    for (int j = s + lane; j < epos; j += 64) {
        float4 t = y4[rowlist[j]];
        ax += t.x; ay += t.y; az += t.z;
    }
#pragma unroll
    for (int d = 1; d < 64; d <<= 1) {
        ax += __shfl_xor(ax, d);
        ay += __shfl_xor(ay, d);
        az += __shfl_xor(az, d);
    }
    float dn = dinv[n];
    float h1 = fmaxf(fmaf(dn, ax * W1l[lane] + ay * W1l[64 + lane] + az * W1l[128 + lane],
                          b1[lane]), 0.0f);
    float acc2 = 0.f;
#pragma unroll
    for (int k = 0; k < 64; k++) {
        float hk = bcast_lane(h1, k);
        acc2 = fmaf(hk, W2l[k * 64 + lane], acc2);
    }
    g2[(size_t)n * 64 + lane] = dn * acc2;
}

// ---- gather-aggregate (LDS-free, latency-bound -> 8-deep MLP) ------------
__global__ void k_gather(const float* __restrict__ g, const int* __restrict__ off,
                         const int* __restrict__ rl, const float* __restrict__ dinv,
                         const float* __restrict__ b, float* __restrict__ h, int N) {
    int tid = threadIdx.x;
    int wave = tid >> 6, lane = tid & 63;
    int n = blockIdx.x * 4 + wave;
    if (n >= N) return;
    int s = off[n], epos = off[n + 1];
    float a0 = g[(size_t)n * 64 + lane];
    float a1 = 0.f, a2 = 0.f, a3 = 0.f;
    float a4 = 0.f, a5 = 0.f, a6 = 0.f, a7 = 0.f;
    int j = s;
    for (; j + 7 < epos; j += 8) {
        int r0 = rl[j],     r1 = rl[j + 1], r2 = rl[j + 2], r3 = rl[j + 3];
        int r4 = rl[j + 4], r5 = rl[j + 5], r6 = rl[j + 6], r7 = rl[j + 7];
        a0 += g[(size_t)r0 * 64 + lane];
        a1 += g[(size_t)r1 * 64 + lane];
        a2 += g[(size_t)r2 * 64 + lane];
        a3 += g[(size_t)r3 * 64 + lane];
        a4 += g[(size_t)r4 * 64 + lane];
        a5 += g[(size_t)r5 * 64 + lane];
        a6 += g[(size_t)r6 * 64 + lane];
        a7 += g[(size_t)r7 * 64 + lane];
    }
    for (; j < epos; j++) a1 += g[(size_t)rl[j] * 64 + lane];
    float acc = ((a0 + a1) + (a2 + a3)) + ((a4 + a5) + (a6 + a7));
    h[(size_t)n * 64 + lane] = fmaxf(fmaf(dinv[n], acc, b[lane]), 0.0f);
}

// ---- edge-MLP precompute: WEIGHTS IN REGISTERS (zero LDS) ----------------
//      Scalar-LDS body is LDS-issue-bound (128 ds_read_b32/node ~ 742cyc).
//      Each lane holds column `lane` of Wa,Wb in 128 VGPRs (constant-index
//      arrays under full unroll -> register-promoted; launch_bounds(256,1)
//      grants the budget). Inner loop = pure VALU: readlane->SGPR broadcast
//      + FMA. LDS restructures (float2/float4) spilled catastrophically
//      (rounds 16/20); this removes the LDS pipe from the kernel entirely.
__global__ void __launch_bounds__(256, 1)
k_lin3(float* __restrict__ h, const float* __restrict__ W3,
       const float* __restrict__ b3, float* __restrict__ u, int N) {
    int tid = threadIdx.x;
    int wave = tid >> 6, lane = tid & 63;
    float wa[64], wb[64];
#pragma unroll
    for (int k = 0; k < 64; k++) {
        wa[k] = W3[k * 64 + lane];
        wb[k] = W3[4096 + k * 64 + lane];
    }
    float bb = b3[lane];
    int gid = blockIdx.x * 4 + wave;
    int stride = gridDim.x * 4;
    for (int n = gid; n < N; n += stride) {
        float hv = h[(size_t)n * 64 + lane];
        float ua = bb, va = 0.f;
#pragma unroll
        for (int k = 0; k < 64; k++) {
            float hk = bcast_lane(hv, k);
            ua = fmaf(hk, wa[k], ua);
            va = fmaf(hk, wb[k], va);
        }
        u[(size_t)n * 64 + lane] = ua;
        h[(size_t)n * 64 + lane] = va;  // v in place over h2 (lane-local row)
    }
}

// ---- edge scorer, CSR order, SEQUENTIAL writes to tmp --------------------
__global__ void k_edge_csr(const float4* __restrict__ u4, const float4* __restrict__ v4,
                           const int* __restrict__ off, const int* __restrict__ rowlist,
                           const float4* __restrict__ w44, const float* __restrict__ b4,
                           float* __restrict__ tmp, int N) {
    int tid = threadIdx.x;
    int wave = tid >> 6, lane = tid & 63;
    int n = blockIdx.x * 4 + wave;
    if (n >= N) return;
    int c16 = lane & 15, grp = lane >> 4;
    int s = off[n], epos = off[n + 1];
    float4 vv = v4[(size_t)n * 16 + c16];
    float4 w = w44[c16];
    float bb = b4[0];
    for (int j0 = s; j0 < epos; j0 += 16) {
        int ja = j0 + grp, jb = j0 + 4 + grp, jc = j0 + 8 + grp, jd = j0 + 12 + grp;
        bool va_ = ja < epos, vb_ = jb < epos, vc_ = jc < epos, vd_ = jd < epos;
        int ra = va_ ? rowlist[ja] : 0;
        int rb = vb_ ? rowlist[jb] : 0;
        int rc = vc_ ? rowlist[jc] : 0;
        int rd = vd_ ? rowlist[jd] : 0;
        float4 a = u4[(size_t)ra * 16 + c16];
        float4 b = u4[(size_t)rb * 16 + c16];
        float4 c = u4[(size_t)rc * 16 + c16];
        float4 d = u4[(size_t)rd * 16 + c16];
        float sa = fmaxf(a.x + vv.x, 0.f) * w.x + fmaxf(a.y + vv.y, 0.f) * w.y +
                   fmaxf(a.z + vv.z, 0.f) * w.z + fmaxf(a.w + vv.w, 0.f) * w.w;
        float sb = fmaxf(b.x + vv.x, 0.f) * w.x + fmaxf(b.y + vv.y, 0.f) * w.y +
                   fmaxf(b.z + vv.z, 0.f) * w.z + fmaxf(b.w + vv.w, 0.f) * w.w;
        float sc = fmaxf(c.x + vv.x, 0.f) * w.x + fmaxf(c.y + vv.y, 0.f) * w.y +
                   fmaxf(c.z + vv.z, 0.f) * w.z + fmaxf(c.w + vv.w, 0.f) * w.w;
        float sd = fmaxf(d.x + vv.x, 0.f) * w.x + fmaxf(d.y + vv.y, 0.f) * w.y +
                   fmaxf(d.z + vv.z, 0.f) * w.z + fmaxf(d.w + vv.w, 0.f) * w.w;
        sa += __shfl_xor(sa, 1); sa += __shfl_xor(sa, 2);
        sa += __shfl_xor(sa, 4); sa += __shfl_xor(sa, 8);
        sb += __shfl_xor(sb, 1); sb += __shfl_xor(sb, 2);
        sb += __shfl_xor(sb, 4); sb += __shfl_xor(sb, 8);
        sc += __shfl_xor(sc, 1); sc += __shfl_xor(sc, 2);
        sc += __shfl_xor(sc, 4); sc += __shfl_xor(sc, 8);
        sd += __shfl_xor(sd, 1); sd += __shfl_xor(sd, 2);
        sd += __shfl_xor(sd, 4); sd += __shfl_xor(sd, 8);
        if (c16 == 0) {
            if (va_) tmp[ja] = sa + bb;
            if (vb_) tmp[jb] = sb + bb;
            if (vc_) tmp[jc] = sc + bb;
            if (vd_) tmp[jd] = sd + bb;
        }
    }
}

// ---- final permute: out[e] = tmp[pos[e]] ---------------------------------
__global__ void k_perm(const float* __restrict__ tmp, const int* __restrict__ pos,
                       float* __restrict__ out, int E) {
    int e = blockIdx.x * blockDim.x + threadIdx.x;
    if (e < E) out[e] = tmp[pos[e]];
}

extern "C" void kernel_launch(void* const* d_in, const int* in_sizes, int n_in,
                              void* d_out, int out_size, void* d_ws, size_t ws_size,
                              hipStream_t stream) {
    const float* x  = (const float*)d_in[0];
    const int*   ei = (const int*)d_in[1];
    const float* W1 = (const float*)d_in[2];
    const float* b1 = (const float*)d_in[3];
    const float* W2 = (const float*)d_in[4];
    const float* b2 = (const float*)d_in[5];
    const float* W3 = (const float*)d_in[6];
    const float* b3 = (const float*)d_in[7];
    const float* W4 = (const float*)d_in[8];
    const float* b4 = (const float*)d_in[9];
    int N = in_sizes[0] / 3;
    int E = in_sizes[1] / 2;
    const int* row = ei;
    const int* col = ei + E;
    float* out = (float*)d_out;

    char* ws = (char*)d_ws;
    size_t off_b = 0;
    auto alloc = [&](size_t bytes) {
        void* p = ws + off_b;
        off_b += (bytes + 255) & ~(size_t)255;
        return p;
    };
    float* dinv    = (float*)alloc((size_t)N * 4);
    int*   offs    = (int*)alloc((size_t)(N + 1) * 4);
    int*   bsum    = (int*)alloc(512 * 4);
    float* bufA    = (float*)alloc((size_t)N * 64 * 4);   // ints; g2; u
    float* bufB    = (float*)alloc((size_t)N * 64 * 4);   // y4+lrank; h2/v
    int*   rowlist = (int*)alloc((size_t)E * 4);
    int*   pos     = (int*)alloc((size_t)E * 4);
    float* tmp     = (float*)alloc((size_t)E * 4);

    // aliases into bufA (all dead before k_layer12 writes g2=bufA):
    int* part    = (int*)bufA;              // N
    int* deg     = (int*)bufA + N;          // N
    int* gcounts = (int*)bufA + 2 * N;      // 32N = 12.8MB (fits: 34N < 64N)
    // aliases into bufB (dead before k_gather writes h2=bufB):
    float4* y4   = (float4*)bufB;           // 4N floats
    int*   lrank = (int*)bufB + (size_t)4 * N;  // E ints

    dim3 B(256);
    int nbN     = (N + 255) / 256;
    int nbE     = (E + 255) / 256;
    int nbNode4 = (N + 3) / 4;

    // --- CSR build (LDS-histogram, zero global atomics) + normalization ---
    k_lhist<<<NRANGE * NCHUNK, 1024, 0, stream>>>(col, lrank, gcounts, E, N);
    k_gbase<<<nbN, B, 0, stream>>>(gcounts, deg, N);
    k_scan1<<<nbN, B, 0, stream>>>(deg, part, bsum, N);
    k_scan2<<<1, 512, 0, stream>>>(bsum, nbN);
    k_scan3d<<<nbN, B, 0, stream>>>(part, bsum, deg, x, offs, dinv, y4, N, E);
    k_posL<<<nbE, B, 0, stream>>>(col, lrank, offs, gcounts, pos, E, N);
    k_fillr<<<2048, B, 0, stream>>>(row, pos, rowlist, E);

    // --- fused layer1 + lin2: writes g2=bufA ---
    k_layer12<<<nbNode4, B, 0, stream>>>(y4, offs, rowlist, dinv, W1, b1, W2, bufA, N);
    // --- layer 2 aggregate: h2=bufB ---
    k_gather<<<nbNode4, B, 0, stream>>>(bufA, offs, rowlist, dinv, b2, bufB, N);
    // --- edge MLP precompute: u=bufA (over dead g2), v in place over h2 ---
    k_lin3<<<1280, B, 0, stream>>>(bufB, W3, b3, bufA, N);
    // --- edge scorer to tmp (CSR order), then permute to edge order ---
    k_edge_csr<<<nbNode4, B, 0, stream>>>((const float4*)bufA, (const float4*)bufB,
                                          offs, rowlist, (const float4*)W4, b4, tmp, N);
    k_perm<<<nbE, B, 0, stream>>>(tmp, pos, out, E);
}